// Round 7
// baseline (290.408 us; speedup 1.0000x reference)
//
#include <hip/hip_runtime.h>
#include <math.h>

#define DD 1024
#define HH 2048
#define NBLK 64

typedef float f32x4 __attribute__((ext_vector_type(4)));
typedef short short8 __attribute__((ext_vector_type(8)));

__device__ __forceinline__ float b2f(unsigned short u) {
    return __uint_as_float(((unsigned int)u) << 16);
}
__device__ __forceinline__ unsigned short f2b(float f) {
    unsigned int x = __float_as_uint(f);
    unsigned int r = (x + 0x7FFFu + ((x >> 16) & 1u)) >> 16;
    return (unsigned short)r;
}

// ---------------- merged precompute ----------------
// blocks: [0,2048) f2b W3->W3b | [2048,2560) W1T | [2560,3584) W2T | [3584,4096) W3T
//         [4096,4104) c1 = W1^T b3
__global__ __launch_bounds__(256) void k_pre(const float* __restrict__ W1,
                                             const float* __restrict__ W2,
                                             const float* __restrict__ W3,
                                             const float* __restrict__ b3,
                                             unsigned short* __restrict__ W1T,
                                             unsigned short* __restrict__ W2T,
                                             unsigned short* __restrict__ W3T,
                                             unsigned short* __restrict__ W3b,
                                             float* __restrict__ c1) {
    __shared__ float tile[64][65];
    const int b = blockIdx.x, t = threadIdx.x;
    if (b < 2048) {
        int i = (b * 256 + t) * 4;
        float4 v = *(const float4*)(W3 + i);
        ushort4 o;
        o.x = f2b(v.x); o.y = f2b(v.y); o.z = f2b(v.z); o.w = f2b(v.w);
        *(ushort4*)(W3b + i) = o;
        return;
    }
    if (b >= 4096) {
        int m = ((b - 4096) << 8) + t;
        float acc = 0.f;
        for (int i = 0; i < DD; ++i) acc += W1[(size_t)i * HH + m] * b3[i];
        c1[m] = acc;
        return;
    }
    const float* in; unsigned short* out; int R, C, bx, by;
    if (b < 2560)      { int bb = b - 2048; in = W1; out = W1T; R = DD; C = HH; bx = bb & 31; by = bb >> 5; }
    else if (b < 3584) { int bb = b - 2560; in = W2; out = W2T; R = HH; C = HH; bx = bb & 31; by = bb >> 5; }
    else               { int bb = b - 3584; in = W3; out = W3T; R = HH; C = DD; bx = bb & 15; by = bb >> 4; }
    const int c0 = bx * 64, r0 = by * 64;
    const int cc = t & 63, rb = t >> 6;
    #pragma unroll
    for (int p = 0; p < 16; ++p) {
        int rr = p * 4 + rb;
        tile[rr][cc] = in[(size_t)(r0 + rr) * C + c0 + cc];
    }
    __syncthreads();
    #pragma unroll
    for (int p = 0; p < 16; ++p) {
        int rr = p * 4 + rb;
        out[(size_t)(c0 + rr) * R + r0 + cc] = f2b(tile[cc][rr]);
    }
}

// ---------------- M = W1^T @ W3^T (bf16), P = M .* W2 (bf16); + barrier zero ----------------
__global__ __launch_bounds__(256) void k_gemmP(const unsigned short* __restrict__ W1T,
                                               const unsigned short* __restrict__ W3b,
                                               const float* __restrict__ W2,
                                               unsigned short* __restrict__ Mb,
                                               unsigned short* __restrict__ Pb,
                                               unsigned* __restrict__ bar) {
    const int t = threadIdx.x;
    if (blockIdx.x == 0 && blockIdx.y == 0 && t < 64) {
        #pragma unroll
        for (int q = 0; q < 9; ++q) bar[t + q * 64] = 0u;
    }
    __shared__ unsigned short At[128][40];
    __shared__ unsigned short Bt[128][40];
    const int m0 = blockIdx.y * 128;
    const int k0 = blockIdx.x * 128;
    const int r = t & 127, half = t >> 7;
    const int wv = t >> 6, l = t & 63;
    const int wr = wv >> 1, wc = wv & 1;
    const int fr = l & 15, fg = l >> 4;

    f32x4 acc[4][4] = {};
    for (int i0 = 0; i0 < DD; i0 += 32) {
        {
            const float4* sa = (const float4*)(W1T + (size_t)(m0 + r) * DD + i0 + half * 16);
            const float4* sb = (const float4*)(W3b + (size_t)(k0 + r) * DD + i0 + half * 16);
            float4 a0 = sa[0], a1 = sa[1];
            float4 b0 = sb[0], b1 = sb[1];
            float4* da = (float4*)&At[r][half * 16];
            float4* db = (float4*)&Bt[r][half * 16];
            da[0] = a0; da[1] = a1;
            db[0] = b0; db[1] = b1;
        }
        __syncthreads();
        short8 af[4], bf[4];
        #pragma unroll
        for (int a = 0; a < 4; ++a)
            af[a] = *(const short8*)&At[wr * 64 + a * 16 + fr][fg * 8];
        #pragma unroll
        for (int b = 0; b < 4; ++b)
            bf[b] = *(const short8*)&Bt[wc * 64 + b * 16 + fr][fg * 8];
        #pragma unroll
        for (int a = 0; a < 4; ++a)
            #pragma unroll
            for (int b = 0; b < 4; ++b)
                acc[a][b] = __builtin_amdgcn_mfma_f32_16x16x32_bf16(af[a], bf[b], acc[a][b], 0, 0, 0);
        __syncthreads();
    }
    #pragma unroll
    for (int a = 0; a < 4; ++a) {
        #pragma unroll
        for (int b = 0; b < 4; ++b) {
            #pragma unroll
            for (int j = 0; j < 4; ++j) {
                int row = m0 + wr * 64 + a * 16 + fg * 4 + j;
                int col = k0 + wc * 64 + b * 16 + fr;
                size_t idx = (size_t)row * HH + col;
                float m = acc[a][b][j];
                Mb[idx] = f2b(m);
                Pb[idx] = f2b(m * W2[idx]);
            }
        }
    }
}

// ---------------- tree grid barrier: 8 sectors x 8 blocks, device-scope RMWs ----------------
__device__ __forceinline__ void gbar(unsigned* bar, int b, unsigned g) {
    __syncthreads();
    if (threadIdx.x == 0) {
        const int sec = b >> 3;
        unsigned* scnt = bar + sec * 32;          // lines 0..7
        unsigned* rcnt = bar + 256;               // line 8
        unsigned* gen  = bar + 288;               // line 9
        unsigned* sgen = bar + 320 + sec * 32;    // lines 10..17
        __threadfence();
        unsigned a = atomicAdd(scnt, 1u);
        if (a == 8u * g - 1u) {
            unsigned r2 = atomicAdd(rcnt, 1u);
            if (r2 == 8u * g - 1u) atomicExch(gen, g);
            else while (atomicOr(gen, 0u) < g) __builtin_amdgcn_s_sleep(1);
            atomicExch(sgen, g);
        } else {
            while (atomicOr(sgen, 0u) < g) __builtin_amdgcn_s_sleep(1);
        }
        __threadfence();
    }
    __syncthreads();
}

// ---------------- persistent RK4 chain: 64 blocks x 16 waves, 2 barriers/stage ----------------
__global__ __launch_bounds__(1024) void k_chain(
    const unsigned short* __restrict__ Mb,   // [2048][2048] M = W1^T W3^T
    const unsigned short* __restrict__ Pb,   // [2048][2048] P = M .* W2
    const unsigned short* __restrict__ W1T,  // [2048][1024]
    const unsigned short* __restrict__ W2T,  // [2048][2048]
    const unsigned short* __restrict__ W3T,  // [1024][2048]
    const float* __restrict__ x0,
    const float* __restrict__ b1, const float* __restrict__ wt,
    const float* __restrict__ b2, const float* __restrict__ b3,
    const float* __restrict__ c1,
    float* __restrict__ h1_g, float* __restrict__ h2_g, float* __restrict__ hacc_g,
    float* __restrict__ divpart, float* __restrict__ out,
    unsigned* __restrict__ bar) {
    __shared__ float vecH[2048];
    __shared__ float vecW[2048];
    __shared__ float wred[16];
    const int t = threadIdx.x, b = blockIdx.x;
    const int wib = t >> 6, lane = t & 63;
    const int gw = (b << 4) + wib;   // 0..1023
    const int m0 = gw << 1;          // 2 owned h-rows
    const int j0 = gw;               // 1 owned x-row
    unsigned g = 0;

    const float bb1_0 = b1[m0], bb1_1 = b1[m0 + 1];
    const float wt_0 = wt[m0], wt_1 = wt[m0 + 1];
    const float bb2_0 = b2[m0], bb2_1 = b2[m0 + 1];
    const float c1_0 = c1[m0], c1_1 = c1[m0 + 1];

    float A1_0, A1_1;
    float u0 = 0.f, u1 = 0.f;
    float hc0 = 0.f, hc1 = 0.f;
    float wdiv = 0.f;

    float logq_r = 0.f;
    if (b == 0 && wib == 0) {
        float ssum = 0.f;
        #pragma unroll
        for (int q = 0; q < 16; ++q) { float xv = x0[lane + (q << 6)]; ssum += xv * xv; }
        #pragma unroll
        for (int o = 1; o < 64; o <<= 1) ssum += __shfl_xor(ssum, o, 64);
        logq_r = -0.5f * ssum - 0.5f * 1024.0f * 1.8378770664093453f;
    }

    for (int s = 0; s < 8; ++s) {
        const int ss = s & 3;
        const float tcur = (s >> 2) * 0.5f + ((ss == 0) ? 0.f : (ss == 3) ? 0.5f : 0.25f);

        // ================= Phase A: h1 (+ div ride-along for stage s-1) =================
        if (s == 0) {
            if (t < 256) ((float4*)vecH)[t] = ((const float4*)x0)[t];
            __syncthreads();
            float a0 = 0.f, a1 = 0.f;
            const unsigned short* Wr = W1T + (size_t)m0 * DD;
            #pragma unroll
            for (int rep = 0; rep < 2; ++rep) {
                const int idx = rep * 512 + lane * 8;
                short8 r0 = *(const short8*)(Wr + idx);
                short8 r1 = *(const short8*)(Wr + DD + idx);
                float4 hA = *(const float4*)(vecH + idx);
                float4 hB = *(const float4*)(vecH + idx + 4);
                float hv[8] = {hA.x, hA.y, hA.z, hA.w, hB.x, hB.y, hB.z, hB.w};
                #pragma unroll
                for (int e = 0; e < 8; ++e) {
                    a0 += b2f((unsigned short)r0[e]) * hv[e];
                    a1 += b2f((unsigned short)r1[e]) * hv[e];
                }
            }
            #pragma unroll
            for (int o = 1; o < 64; o <<= 1) {
                a0 += __shfl_xor(a0, o, 64); a1 += __shfl_xor(a1, o, 64);
            }
            A1_0 = a0; A1_1 = a1;
            float h0 = tanhf(A1_0 + bb1_0 + tcur * wt_0);
            float h1v = tanhf(A1_1 + bb1_1 + tcur * wt_1);
            u0 = 1.f - h0 * h0; u1 = 1.f - h1v * h1v;
            if (lane == 0) *(float2*)(h1_g + m0) = make_float2(h0, h1v);
        } else {
            if (t < 512) {
                float4 ha = ((const float4*)h2_g)[t];
                float4 sa;
                if (ss == 0) sa = ((const float4*)hacc_g)[t];
                else         sa = ha;
                ((float4*)vecH)[t] = sa;
                ((float4*)vecW)[t] = make_float4(1.f - ha.x * ha.x, 1.f - ha.y * ha.y,
                                                 1.f - ha.z * ha.z, 1.f - ha.w * ha.w);
            }
            __syncthreads();
            float md0 = 0.f, md1 = 0.f, pd0 = 0.f, pd1 = 0.f;
            const unsigned short* Mr = Mb + (size_t)m0 * HH;
            const unsigned short* Pr = Pb + (size_t)m0 * HH;
            #pragma unroll
            for (int rep = 0; rep < 4; ++rep) {
                const int idx = rep * 512 + lane * 8;
                short8 m0v = *(const short8*)(Mr + idx);
                short8 m1v = *(const short8*)(Mr + HH + idx);
                short8 p0v = *(const short8*)(Pr + idx);
                short8 p1v = *(const short8*)(Pr + HH + idx);
                float4 hA = *(const float4*)(vecH + idx);
                float4 hB = *(const float4*)(vecH + idx + 4);
                float4 wA = *(const float4*)(vecW + idx);
                float4 wB = *(const float4*)(vecW + idx + 4);
                float hv[8] = {hA.x, hA.y, hA.z, hA.w, hB.x, hB.y, hB.z, hB.w};
                float wv[8] = {wA.x, wA.y, wA.z, wA.w, wB.x, wB.y, wB.z, wB.w};
                #pragma unroll
                for (int e = 0; e < 8; ++e) {
                    md0 += b2f((unsigned short)m0v[e]) * hv[e];
                    md1 += b2f((unsigned short)m1v[e]) * hv[e];
                    pd0 += b2f((unsigned short)p0v[e]) * wv[e];
                    pd1 += b2f((unsigned short)p1v[e]) * wv[e];
                }
            }
            #pragma unroll
            for (int o = 1; o < 64; o <<= 1) {
                md0 += __shfl_xor(md0, o, 64); md1 += __shfl_xor(md1, o, 64);
                pd0 += __shfl_xor(pd0, o, 64); pd1 += __shfl_xor(pd1, o, 64);
            }
            const int sp = (s - 1) & 3;
            const float cprev = (sp == 1 || sp == 2) ? (1.f / 6.f) : (1.f / 12.f);
            wdiv += cprev * (u0 * pd0 + u1 * pd1);
            float pre0, pre1;
            if (ss == 0) {                      // step boundary: A1 += M*hacc + dt*c1
                A1_0 += md0 + 0.5f * c1_0; A1_1 += md1 + 0.5f * c1_1;
                pre0 = A1_0 + bb1_0 + tcur * wt_0; pre1 = A1_1 + bb1_1 + tcur * wt_1;
            } else {
                const float a = (ss == 3) ? 0.5f : 0.25f;
                pre0 = A1_0 + a * (md0 + c1_0) + bb1_0 + tcur * wt_0;
                pre1 = A1_1 + a * (md1 + c1_1) + bb1_1 + tcur * wt_1;
            }
            float h0 = tanhf(pre0), h1v = tanhf(pre1);
            u0 = 1.f - h0 * h0; u1 = 1.f - h1v * h1v;
            if (lane == 0) *(float2*)(h1_g + m0) = make_float2(h0, h1v);
        }
        gbar(bar, b, ++g);

        // ================= Phase B: h2 = tanh(W2^T h1 + b2) =================
        if (t < 512) ((float4*)vecH)[t] = ((const float4*)h1_g)[t];
        __syncthreads();
        {
            float a0 = 0.f, a1 = 0.f;
            const unsigned short* Wr = W2T + (size_t)m0 * HH;
            #pragma unroll
            for (int rep = 0; rep < 4; ++rep) {
                const int idx = rep * 512 + lane * 8;
                short8 r0 = *(const short8*)(Wr + idx);
                short8 r1 = *(const short8*)(Wr + HH + idx);
                float4 hA = *(const float4*)(vecH + idx);
                float4 hB = *(const float4*)(vecH + idx + 4);
                float hv[8] = {hA.x, hA.y, hA.z, hA.w, hB.x, hB.y, hB.z, hB.w};
                #pragma unroll
                for (int e = 0; e < 8; ++e) {
                    a0 += b2f((unsigned short)r0[e]) * hv[e];
                    a1 += b2f((unsigned short)r1[e]) * hv[e];
                }
            }
            #pragma unroll
            for (int o = 1; o < 64; o <<= 1) {
                a0 += __shfl_xor(a0, o, 64); a1 += __shfl_xor(a1, o, 64);
            }
            float q0 = tanhf(a0 + bb2_0), q1 = tanhf(a1 + bb2_1);
            const float cs = (ss == 1 || ss == 2) ? (1.f / 6.f) : (1.f / 12.f);
            hc0 += cs * q0; hc1 += cs * q1;
            if (lane == 0) {
                *(float2*)(h2_g + m0) = make_float2(q0, q1);
                if (ss == 3) *(float2*)(hacc_g + m0) = make_float2(hc0, hc1);
            }
        }
        gbar(bar, b, ++g);
    }

    // ================= Epilogue: last div + x_out + logq =================
    {
        if (t < 512) {
            float4 ha = ((const float4*)h2_g)[t];
            ((float4*)vecH)[t] = ((const float4*)hacc_g)[t];
            ((float4*)vecW)[t] = make_float4(1.f - ha.x * ha.x, 1.f - ha.y * ha.y,
                                             1.f - ha.z * ha.z, 1.f - ha.w * ha.w);
        }
        __syncthreads();
        float pd0 = 0.f, pd1 = 0.f, xo0 = 0.f;
        const unsigned short* Pr = Pb + (size_t)m0 * HH;
        const unsigned short* Vr = W3T + (size_t)j0 * HH;
        #pragma unroll
        for (int rep = 0; rep < 4; ++rep) {
            const int idx = rep * 512 + lane * 8;
            short8 p0v = *(const short8*)(Pr + idx);
            short8 p1v = *(const short8*)(Pr + HH + idx);
            short8 v0v = *(const short8*)(Vr + idx);
            float4 hA = *(const float4*)(vecH + idx);
            float4 hB = *(const float4*)(vecH + idx + 4);
            float4 wA = *(const float4*)(vecW + idx);
            float4 wB = *(const float4*)(vecW + idx + 4);
            float hv[8] = {hA.x, hA.y, hA.z, hA.w, hB.x, hB.y, hB.z, hB.w};
            float wv[8] = {wA.x, wA.y, wA.z, wA.w, wB.x, wB.y, wB.z, wB.w};
            #pragma unroll
            for (int e = 0; e < 8; ++e) {
                pd0 += b2f((unsigned short)p0v[e]) * wv[e];
                pd1 += b2f((unsigned short)p1v[e]) * wv[e];
                xo0 += b2f((unsigned short)v0v[e]) * hv[e];
            }
        }
        #pragma unroll
        for (int o = 1; o < 64; o <<= 1) {
            pd0 += __shfl_xor(pd0, o, 64); pd1 += __shfl_xor(pd1, o, 64);
            xo0 += __shfl_xor(xo0, o, 64);
        }
        wdiv += (1.f / 12.f) * (u0 * pd0 + u1 * pd1);
        if (lane == 0) {
            out[j0] = x0[j0] + xo0 + b3[j0];
            wred[wib] = wdiv;
        }
    }
    __syncthreads();
    if (t == 0) {
        float dsum = 0.f;
        #pragma unroll
        for (int q = 0; q < 16; ++q) dsum += wred[q];
        divpart[b] = dsum;
    }
    gbar(bar, b, ++g);
    if (b == 0 && wib == 0) {
        float d = divpart[lane];
        #pragma unroll
        for (int o = 1; o < 64; o <<= 1) d += __shfl_xor(d, o, 64);
        if (lane == 0) out[DD] = logq_r - d;
    }
}

extern "C" void kernel_launch(void* const* d_in, const int* in_sizes, int n_in,
                              void* d_out, int out_size, void* d_ws, size_t ws_size,
                              hipStream_t stream) {
    const float* x0 = (const float*)d_in[0];
    const float* W1 = (const float*)d_in[1];
    const float* b1 = (const float*)d_in[2];
    const float* wt = (const float*)d_in[3];
    const float* W2 = (const float*)d_in[4];
    const float* b2 = (const float*)d_in[5];
    const float* W3 = (const float*)d_in[6];
    const float* b3 = (const float*)d_in[7];
    float* out = (float*)d_out;

    char* ws = (char*)d_ws;
    const size_t MB = 1024 * 1024;
    unsigned short* Pb  = (unsigned short*)(ws);            // 8 MB
    unsigned short* W1T = (unsigned short*)(ws + 8 * MB);   // 4 MB
    unsigned short* W3b = (unsigned short*)(ws + 12 * MB);  // 4 MB
    unsigned short* W2T = (unsigned short*)(ws + 16 * MB);  // 8 MB
    unsigned short* W3T = (unsigned short*)(ws + 24 * MB);  // 4 MB
    unsigned short* Mb  = (unsigned short*)(ws + 28 * MB);  // 8 MB
    float* fb = (float*)(ws + 36 * MB);
    float* h1_g    = fb;                       // 2048
    float* h2_g    = fb + 2048;                // 2048
    float* hacc_g  = fb + 4096;                // 2048
    float* c1      = fb + 6144;                // 2048
    float* divpart = fb + 8192;                // 64
    unsigned* bar  = (unsigned*)(fb + 8448);   // 576 uints

    k_pre<<<4104, 256, 0, stream>>>(W1, W2, W3, b3, W1T, W2T, W3T, W3b, c1);
    k_gemmP<<<dim3(16, 16), 256, 0, stream>>>(W1T, W3b, W2, Mb, Pb, bar);
    k_chain<<<NBLK, 1024, 0, stream>>>(Mb, Pb, W1T, W2T, W3T, x0, b1, wt, b2, b3, c1,
                                       h1_g, h2_g, hacc_g, divpart, out, bar);
}

// Round 8
// 202.440 us; speedup vs baseline: 1.4345x; 1.4345x over previous
//
#include <hip/hip_runtime.h>
#include <math.h>

#define DD 1024
#define HH 2048
#define NBLK 128          // compute blocks; block NBLK is the barrier checker
#define NBAR 17

typedef float f32x4 __attribute__((ext_vector_type(4)));
typedef short short8 __attribute__((ext_vector_type(8)));

__device__ __forceinline__ float b2f(unsigned short u) {
    return __uint_as_float(((unsigned int)u) << 16);
}
__device__ __forceinline__ unsigned short f2b(float f) {
    unsigned int x = __float_as_uint(f);
    unsigned int r = (x + 0x7FFFu + ((x >> 16) & 1u)) >> 16;
    return (unsigned short)r;
}

// ---------------- merged precompute ----------------
// blocks: [0,2048) f2b W3->W3b | [2048,2560) W1T | [2560,3584) W2T | [3584,4096) W3T
//         [4096,4104) c1 = W1^T b3
__global__ __launch_bounds__(256) void k_pre(const float* __restrict__ W1,
                                             const float* __restrict__ W2,
                                             const float* __restrict__ W3,
                                             const float* __restrict__ b3,
                                             unsigned short* __restrict__ W1T,
                                             unsigned short* __restrict__ W2T,
                                             unsigned short* __restrict__ W3T,
                                             unsigned short* __restrict__ W3b,
                                             float* __restrict__ c1) {
    __shared__ float tile[64][65];
    const int b = blockIdx.x, t = threadIdx.x;
    if (b < 2048) {
        int i = (b * 256 + t) * 4;
        float4 v = *(const float4*)(W3 + i);
        ushort4 o;
        o.x = f2b(v.x); o.y = f2b(v.y); o.z = f2b(v.z); o.w = f2b(v.w);
        *(ushort4*)(W3b + i) = o;
        return;
    }
    if (b >= 4096) {
        int m = ((b - 4096) << 8) + t;
        float acc = 0.f;
        for (int i = 0; i < DD; ++i) acc += W1[(size_t)i * HH + m] * b3[i];
        c1[m] = acc;
        return;
    }
    const float* in; unsigned short* out; int R, C, bx, by;
    if (b < 2560)      { int bb = b - 2048; in = W1; out = W1T; R = DD; C = HH; bx = bb & 31; by = bb >> 5; }
    else if (b < 3584) { int bb = b - 2560; in = W2; out = W2T; R = HH; C = HH; bx = bb & 31; by = bb >> 5; }
    else               { int bb = b - 3584; in = W3; out = W3T; R = HH; C = DD; bx = bb & 15; by = bb >> 4; }
    const int c0 = bx * 64, r0 = by * 64;
    const int cc = t & 63, rb = t >> 6;
    #pragma unroll
    for (int p = 0; p < 16; ++p) {
        int rr = p * 4 + rb;
        tile[rr][cc] = in[(size_t)(r0 + rr) * C + c0 + cc];
    }
    __syncthreads();
    #pragma unroll
    for (int p = 0; p < 16; ++p) {
        int rr = p * 4 + rb;
        out[(size_t)(c0 + rr) * R + r0 + cc] = f2b(tile[cc][rr]);
    }
}

// ---------------- M = W1^T @ W3^T (bf16), P = M .* W2 (bf16); + flag/gen zero ----------------
__global__ __launch_bounds__(256) void k_gemmP(const unsigned short* __restrict__ W1T,
                                               const unsigned short* __restrict__ W3b,
                                               const float* __restrict__ W2,
                                               unsigned short* __restrict__ Mb,
                                               unsigned short* __restrict__ Pb,
                                               unsigned* __restrict__ flags) {
    const int t = threadIdx.x;
    if (blockIdx.x == 0 && blockIdx.y == 0) {
        #pragma unroll
        for (int q = 0; q < 5; ++q) {
            int i = t + q * 256;
            if (i < 1056) flags[i] = 0u;
        }
    }
    __shared__ unsigned short At[128][40];
    __shared__ unsigned short Bt[128][40];
    const int m0 = blockIdx.y * 128;
    const int k0 = blockIdx.x * 128;
    const int r = t & 127, half = t >> 7;
    const int wv = t >> 6, l = t & 63;
    const int wr = wv >> 1, wc = wv & 1;
    const int fr = l & 15, fg = l >> 4;

    f32x4 acc[4][4] = {};
    for (int i0 = 0; i0 < DD; i0 += 32) {
        {
            const float4* sa = (const float4*)(W1T + (size_t)(m0 + r) * DD + i0 + half * 16);
            const float4* sb = (const float4*)(W3b + (size_t)(k0 + r) * DD + i0 + half * 16);
            float4 a0 = sa[0], a1 = sa[1];
            float4 b0 = sb[0], b1 = sb[1];
            float4* da = (float4*)&At[r][half * 16];
            float4* db = (float4*)&Bt[r][half * 16];
            da[0] = a0; da[1] = a1;
            db[0] = b0; db[1] = b1;
        }
        __syncthreads();
        short8 af[4], bf[4];
        #pragma unroll
        for (int a = 0; a < 4; ++a)
            af[a] = *(const short8*)&At[wr * 64 + a * 16 + fr][fg * 8];
        #pragma unroll
        for (int b = 0; b < 4; ++b)
            bf[b] = *(const short8*)&Bt[wc * 64 + b * 16 + fr][fg * 8];
        #pragma unroll
        for (int a = 0; a < 4; ++a)
            #pragma unroll
            for (int b = 0; b < 4; ++b)
                acc[a][b] = __builtin_amdgcn_mfma_f32_16x16x32_bf16(af[a], bf[b], acc[a][b], 0, 0, 0);
        __syncthreads();
    }
    #pragma unroll
    for (int a = 0; a < 4; ++a) {
        #pragma unroll
        for (int b = 0; b < 4; ++b) {
            #pragma unroll
            for (int j = 0; j < 4; ++j) {
                int row = m0 + wr * 64 + a * 16 + fg * 4 + j;
                int col = k0 + wc * 64 + b * 16 + fr;
                size_t idx = (size_t)row * HH + col;
                float m = acc[a][b][j];
                Mb[idx] = f2b(m);
                Pb[idx] = f2b(m * W2[idx]);
            }
        }
    }
}

// ---------------- checker-based grid barrier ----------------
// arrival: fence + relaxed store to own padded flag (no RMW).
// wait: thread 0 polls 'gen' with relaxed agent loads (no RMW), then fence.
// a dedicated checker block aggregates flags -> gen.
__device__ __forceinline__ void gbar(unsigned* flags, unsigned* gen, int b, unsigned g) {
    __syncthreads();
    if (threadIdx.x == 0) {
        __threadfence();
        __hip_atomic_store(&flags[b << 3], g, __ATOMIC_RELAXED, __HIP_MEMORY_SCOPE_AGENT);
        while (__hip_atomic_load(gen, __ATOMIC_RELAXED, __HIP_MEMORY_SCOPE_AGENT) < g)
            __builtin_amdgcn_s_sleep(1);
        __threadfence();
    }
    __syncthreads();
}

// ---------------- persistent RK4 chain: 128 blocks x 8 waves + 1 checker block ----------------
__global__ __launch_bounds__(512) void k_chain(
    const unsigned short* __restrict__ Mb,   // [2048][2048] M = W1^T W3^T
    const unsigned short* __restrict__ Pb,   // [2048][2048] P = M .* W2
    const unsigned short* __restrict__ W1T,  // [2048][1024]
    const unsigned short* __restrict__ W2T,  // [2048][2048]
    const unsigned short* __restrict__ W3T,  // [1024][2048]
    const float* __restrict__ x0,
    const float* __restrict__ b1, const float* __restrict__ wt,
    const float* __restrict__ b2, const float* __restrict__ b3,
    const float* __restrict__ c1,
    float* __restrict__ h1_g, float* __restrict__ h2_g, float* __restrict__ hacc_g,
    float* __restrict__ divpart, float* __restrict__ out,
    unsigned* __restrict__ flags) {
    unsigned* gen = flags + 1024;
    const int t = threadIdx.x, b = blockIdx.x;

    // ---- checker block: poll flags, publish generations, exit ----
    if (b == NBLK) {
        if (t < 64) {
            for (unsigned g = 1; g <= NBAR; ++g) {
                while (true) {
                    unsigned f0 = __hip_atomic_load(&flags[t << 3], __ATOMIC_RELAXED, __HIP_MEMORY_SCOPE_AGENT);
                    unsigned f1 = __hip_atomic_load(&flags[(t + 64) << 3], __ATOMIC_RELAXED, __HIP_MEMORY_SCOPE_AGENT);
                    if (!__any((int)((f0 < g) | (f1 < g)))) break;
                    __builtin_amdgcn_s_sleep(1);
                }
                __threadfence();
                if (t == 0)
                    __hip_atomic_store(gen, g, __ATOMIC_RELAXED, __HIP_MEMORY_SCOPE_AGENT);
            }
        }
        return;
    }

    __shared__ float vecH[2048];
    __shared__ float vecW[2048];
    __shared__ float wred[8];
    const int wib = t >> 6, lane = t & 63;
    const int gw = (b << 3) + wib;   // 0..1023
    const int m0 = gw << 1;          // 2 owned h-rows
    const int j0 = gw;               // 1 owned x-row
    unsigned g = 0;

    const float bb1_0 = b1[m0], bb1_1 = b1[m0 + 1];
    const float wt_0 = wt[m0], wt_1 = wt[m0 + 1];
    const float bb2_0 = b2[m0], bb2_1 = b2[m0 + 1];
    const float c1_0 = c1[m0], c1_1 = c1[m0 + 1];

    float A1_0, A1_1;
    float u0 = 0.f, u1 = 0.f;
    float hc0 = 0.f, hc1 = 0.f;
    float wdiv = 0.f;

    float logq_r = 0.f;
    if (b == 0 && wib == 0) {
        float ssum = 0.f;
        #pragma unroll
        for (int q = 0; q < 16; ++q) { float xv = x0[lane + (q << 6)]; ssum += xv * xv; }
        #pragma unroll
        for (int o = 1; o < 64; o <<= 1) ssum += __shfl_xor(ssum, o, 64);
        logq_r = -0.5f * ssum - 0.5f * 1024.0f * 1.8378770664093453f;
    }

    for (int s = 0; s < 8; ++s) {
        const int ss = s & 3;
        const float tcur = (s >> 2) * 0.5f + ((ss == 0) ? 0.f : (ss == 3) ? 0.5f : 0.25f);

        // ================= Phase A: h1 (+ div ride-along for stage s-1) =================
        if (s == 0) {
            if (t < 256) ((float4*)vecH)[t] = ((const float4*)x0)[t];
            __syncthreads();
            float a0 = 0.f, a1 = 0.f;
            const unsigned short* Wr = W1T + (size_t)m0 * DD;
            #pragma unroll
            for (int rep = 0; rep < 2; ++rep) {
                const int idx = rep * 512 + lane * 8;
                short8 r0 = *(const short8*)(Wr + idx);
                short8 r1 = *(const short8*)(Wr + DD + idx);
                float4 hA = *(const float4*)(vecH + idx);
                float4 hB = *(const float4*)(vecH + idx + 4);
                float hv[8] = {hA.x, hA.y, hA.z, hA.w, hB.x, hB.y, hB.z, hB.w};
                #pragma unroll
                for (int e = 0; e < 8; ++e) {
                    a0 += b2f((unsigned short)r0[e]) * hv[e];
                    a1 += b2f((unsigned short)r1[e]) * hv[e];
                }
            }
            #pragma unroll
            for (int o = 1; o < 64; o <<= 1) {
                a0 += __shfl_xor(a0, o, 64); a1 += __shfl_xor(a1, o, 64);
            }
            A1_0 = a0; A1_1 = a1;
            float h0 = tanhf(A1_0 + bb1_0 + tcur * wt_0);
            float h1v = tanhf(A1_1 + bb1_1 + tcur * wt_1);
            u0 = 1.f - h0 * h0; u1 = 1.f - h1v * h1v;
            if (lane == 0) *(float2*)(h1_g + m0) = make_float2(h0, h1v);
        } else {
            {
                float4 ha = ((const float4*)h2_g)[t];
                float4 sa;
                if (ss == 0) sa = ((const float4*)hacc_g)[t];
                else         sa = ha;
                ((float4*)vecH)[t] = sa;
                ((float4*)vecW)[t] = make_float4(1.f - ha.x * ha.x, 1.f - ha.y * ha.y,
                                                 1.f - ha.z * ha.z, 1.f - ha.w * ha.w);
            }
            __syncthreads();
            float md0 = 0.f, md1 = 0.f, pd0 = 0.f, pd1 = 0.f;
            const unsigned short* Mr = Mb + (size_t)m0 * HH;
            const unsigned short* Pr = Pb + (size_t)m0 * HH;
            #pragma unroll
            for (int rep = 0; rep < 4; ++rep) {
                const int idx = rep * 512 + lane * 8;
                short8 m0v = *(const short8*)(Mr + idx);
                short8 m1v = *(const short8*)(Mr + HH + idx);
                short8 p0v = *(const short8*)(Pr + idx);
                short8 p1v = *(const short8*)(Pr + HH + idx);
                float4 hA = *(const float4*)(vecH + idx);
                float4 hB = *(const float4*)(vecH + idx + 4);
                float4 wA = *(const float4*)(vecW + idx);
                float4 wB = *(const float4*)(vecW + idx + 4);
                float hv[8] = {hA.x, hA.y, hA.z, hA.w, hB.x, hB.y, hB.z, hB.w};
                float wv[8] = {wA.x, wA.y, wA.z, wA.w, wB.x, wB.y, wB.z, wB.w};
                #pragma unroll
                for (int e = 0; e < 8; ++e) {
                    md0 += b2f((unsigned short)m0v[e]) * hv[e];
                    md1 += b2f((unsigned short)m1v[e]) * hv[e];
                    pd0 += b2f((unsigned short)p0v[e]) * wv[e];
                    pd1 += b2f((unsigned short)p1v[e]) * wv[e];
                }
            }
            #pragma unroll
            for (int o = 1; o < 64; o <<= 1) {
                md0 += __shfl_xor(md0, o, 64); md1 += __shfl_xor(md1, o, 64);
                pd0 += __shfl_xor(pd0, o, 64); pd1 += __shfl_xor(pd1, o, 64);
            }
            const int sp = (s - 1) & 3;
            const float cprev = (sp == 1 || sp == 2) ? (1.f / 6.f) : (1.f / 12.f);
            wdiv += cprev * (u0 * pd0 + u1 * pd1);
            float pre0, pre1;
            if (ss == 0) {                      // step boundary: A1 += M*hacc + dt*c1
                A1_0 += md0 + 0.5f * c1_0; A1_1 += md1 + 0.5f * c1_1;
                pre0 = A1_0 + bb1_0 + tcur * wt_0; pre1 = A1_1 + bb1_1 + tcur * wt_1;
            } else {
                const float a = (ss == 3) ? 0.5f : 0.25f;
                pre0 = A1_0 + a * (md0 + c1_0) + bb1_0 + tcur * wt_0;
                pre1 = A1_1 + a * (md1 + c1_1) + bb1_1 + tcur * wt_1;
            }
            float h0 = tanhf(pre0), h1v = tanhf(pre1);
            u0 = 1.f - h0 * h0; u1 = 1.f - h1v * h1v;
            if (lane == 0) *(float2*)(h1_g + m0) = make_float2(h0, h1v);
        }
        gbar(flags, gen, b, ++g);

        // ================= Phase B: h2 = tanh(W2^T h1 + b2) =================
        ((float4*)vecH)[t] = ((const float4*)h1_g)[t];
        __syncthreads();
        {
            float a0 = 0.f, a1 = 0.f;
            const unsigned short* Wr = W2T + (size_t)m0 * HH;
            #pragma unroll
            for (int rep = 0; rep < 4; ++rep) {
                const int idx = rep * 512 + lane * 8;
                short8 r0 = *(const short8*)(Wr + idx);
                short8 r1 = *(const short8*)(Wr + HH + idx);
                float4 hA = *(const float4*)(vecH + idx);
                float4 hB = *(const float4*)(vecH + idx + 4);
                float hv[8] = {hA.x, hA.y, hA.z, hA.w, hB.x, hB.y, hB.z, hB.w};
                #pragma unroll
                for (int e = 0; e < 8; ++e) {
                    a0 += b2f((unsigned short)r0[e]) * hv[e];
                    a1 += b2f((unsigned short)r1[e]) * hv[e];
                }
            }
            #pragma unroll
            for (int o = 1; o < 64; o <<= 1) {
                a0 += __shfl_xor(a0, o, 64); a1 += __shfl_xor(a1, o, 64);
            }
            float q0 = tanhf(a0 + bb2_0), q1 = tanhf(a1 + bb2_1);
            const float cs = (ss == 1 || ss == 2) ? (1.f / 6.f) : (1.f / 12.f);
            hc0 += cs * q0; hc1 += cs * q1;
            if (lane == 0) {
                *(float2*)(h2_g + m0) = make_float2(q0, q1);
                if (ss == 3) *(float2*)(hacc_g + m0) = make_float2(hc0, hc1);
            }
        }
        gbar(flags, gen, b, ++g);
    }

    // ================= Epilogue: last div + x_out + logq =================
    {
        {
            float4 ha = ((const float4*)h2_g)[t];
            ((float4*)vecH)[t] = ((const float4*)hacc_g)[t];
            ((float4*)vecW)[t] = make_float4(1.f - ha.x * ha.x, 1.f - ha.y * ha.y,
                                             1.f - ha.z * ha.z, 1.f - ha.w * ha.w);
        }
        __syncthreads();
        float pd0 = 0.f, pd1 = 0.f, xo0 = 0.f;
        const unsigned short* Pr = Pb + (size_t)m0 * HH;
        const unsigned short* Vr = W3T + (size_t)j0 * HH;
        #pragma unroll
        for (int rep = 0; rep < 4; ++rep) {
            const int idx = rep * 512 + lane * 8;
            short8 p0v = *(const short8*)(Pr + idx);
            short8 p1v = *(const short8*)(Pr + HH + idx);
            short8 v0v = *(const short8*)(Vr + idx);
            float4 hA = *(const float4*)(vecH + idx);
            float4 hB = *(const float4*)(vecH + idx + 4);
            float4 wA = *(const float4*)(vecW + idx);
            float4 wB = *(const float4*)(vecW + idx + 4);
            float hv[8] = {hA.x, hA.y, hA.z, hA.w, hB.x, hB.y, hB.z, hB.w};
            float wv[8] = {wA.x, wA.y, wA.z, wA.w, wB.x, wB.y, wB.z, wB.w};
            #pragma unroll
            for (int e = 0; e < 8; ++e) {
                pd0 += b2f((unsigned short)p0v[e]) * wv[e];
                pd1 += b2f((unsigned short)p1v[e]) * wv[e];
                xo0 += b2f((unsigned short)v0v[e]) * hv[e];
            }
        }
        #pragma unroll
        for (int o = 1; o < 64; o <<= 1) {
            pd0 += __shfl_xor(pd0, o, 64); pd1 += __shfl_xor(pd1, o, 64);
            xo0 += __shfl_xor(xo0, o, 64);
        }
        wdiv += (1.f / 12.f) * (u0 * pd0 + u1 * pd1);
        if (lane == 0) {
            out[j0] = x0[j0] + xo0 + b3[j0];
            wred[wib] = wdiv;
        }
    }
    __syncthreads();
    if (t == 0) {
        float dsum = 0.f;
        #pragma unroll
        for (int q = 0; q < 8; ++q) dsum += wred[q];
        divpart[b] = dsum;
    }
    gbar(flags, gen, b, ++g);
    if (b == 0 && wib == 0) {
        float d = divpart[lane] + divpart[lane + 64];
        #pragma unroll
        for (int o = 1; o < 64; o <<= 1) d += __shfl_xor(d, o, 64);
        if (lane == 0) out[DD] = logq_r - d;
    }
}

extern "C" void kernel_launch(void* const* d_in, const int* in_sizes, int n_in,
                              void* d_out, int out_size, void* d_ws, size_t ws_size,
                              hipStream_t stream) {
    const float* x0 = (const float*)d_in[0];
    const float* W1 = (const float*)d_in[1];
    const float* b1 = (const float*)d_in[2];
    const float* wt = (const float*)d_in[3];
    const float* W2 = (const float*)d_in[4];
    const float* b2 = (const float*)d_in[5];
    const float* W3 = (const float*)d_in[6];
    const float* b3 = (const float*)d_in[7];
    float* out = (float*)d_out;

    char* ws = (char*)d_ws;
    const size_t MB = 1024 * 1024;
    unsigned short* Pb  = (unsigned short*)(ws);            // 8 MB
    unsigned short* W1T = (unsigned short*)(ws + 8 * MB);   // 4 MB
    unsigned short* W3b = (unsigned short*)(ws + 12 * MB);  // 4 MB
    unsigned short* W2T = (unsigned short*)(ws + 16 * MB);  // 8 MB
    unsigned short* W3T = (unsigned short*)(ws + 24 * MB);  // 4 MB
    unsigned short* Mb  = (unsigned short*)(ws + 28 * MB);  // 8 MB
    float* fb = (float*)(ws + 36 * MB);
    float* h1_g    = fb;                       // 2048
    float* h2_g    = fb + 2048;                // 2048
    float* hacc_g  = fb + 4096;                // 2048
    float* c1      = fb + 6144;                // 2048
    float* divpart = fb + 8192;                // 128
    unsigned* flags = (unsigned*)(fb + 8320);  // 1024 padded flags + gen

    k_pre<<<4104, 256, 0, stream>>>(W1, W2, W3, b3, W1T, W2T, W3T, W3b, c1);
    k_gemmP<<<dim3(16, 16), 256, 0, stream>>>(W1T, W3b, W2, Mb, Pb, flags);
    k_chain<<<NBLK + 1, 512, 0, stream>>>(Mb, Pb, W1T, W2T, W3T, x0, b1, wt, b2, b3, c1,
                                          h1_g, h2_g, hacc_g, divpart, out, flags);
}